// Round 10
// baseline (78.315 us; speedup 1.0000x reference)
//
#include <hip/hip_runtime.h>

#define N_NODES 50000
#define N_EDGES 800000
#define DIM 100

#define NB      1563        // coarse buckets of 32 nodes: ceil(50000/32)
#define CAPB    768         // records per bucket region (mean 512, +11 sigma)
#define OVF_CAP 4096
#define EPB     2560        // edges per bin block
#define BIN_BLOCKS 313      // ceil(800000 / 2560)
#define GEMM_BLOCKS 1250    // 50000 / 40
#define ROWS_PB 40          // gemm rows per 256-thread block

// ---------------- workspace layout (bytes) ----------------
#define HIDB_OFF  0u            // bf16 hidden, packed uint[50000*50]   10,000,000
#define GCUR_OFF  10000000u     // int gcur[1563]                            6,256
#define OVFC_OFF  10006256u     // int ovf_cnt (+pad)                           16
#define OVF_OFF   10006272u     // int4 ovf[4096]                           65,536
#define BKT2_OFF  10071808u     // uint2 bkt2[1563*768] (128B-aligned)   9,603,072
#define WT_OFF    19674880u     // float Wt[100*100]                        40,000
#define WS_NEED   19714880u

// float->bf16 RNE helpers
__device__ inline unsigned bf16hi(float v) {            // bf16 in HIGH 16 bits
    unsigned u = __float_as_uint(v);
    u += 0x7FFFu + ((u >> 16) & 1u);
    return u & 0xFFFF0000u;
}
__device__ inline unsigned bf16pair(float lo, float hi) {
    unsigned ulo = __float_as_uint(lo); ulo += 0x7FFFu + ((ulo >> 16) & 1u);
    unsigned uhi = __float_as_uint(hi); uhi += 0x7FFFu + ((uhi >> 16) & 1u);
    return (ulo >> 16) | (uhi & 0xFFFF0000u);
}

// ---------------- transpose + control-buffer zeroing ----------------
__global__ __launch_bounds__(256) void srgnn_transpose(
    const float* __restrict__ W, float* __restrict__ Wt,
    int* __restrict__ gcur, int* __restrict__ ovfc)
{
    const unsigned i = blockIdx.x * 256u + threadIdx.x;
    if (i < DIM * DIM) {
        const int c = i / DIM, k = i - c * DIM;
        Wt[k * DIM + c] = W[i];
    }
    if (i < NB) gcur[i] = 0;
    if (i == 0) *ovfc = 0;
}

// ---------------- fused GEMM + bin, INTERLEAVED roles ---------------------
// bid%5<4 -> gemm block (1250 of them, 40 rows each);
// bid%5==4 -> bin block (313 of them, 2560 edges each).
// Interleaving spreads bin blocks uniformly through the dispatch order so
// they start alongside gemm blocks on every CU: bin's latency-bound
// scatter work fills gemm's FMA-pipeline stalls.
__global__ __launch_bounds__(256) void srgnn_gemm_bin(
    const float* __restrict__ x, const float* __restrict__ Wt,
    const float* __restrict__ b, unsigned* __restrict__ hidU,
    const int* __restrict__ esrc, const int* __restrict__ edst,
    const float* __restrict__ ew, int* __restrict__ gcur,
    int* __restrict__ ovfc, int4* __restrict__ ovf, uint2* __restrict__ bkt2)
{
    __shared__ __align__(16) char smem[16000];
    const int bid = blockIdx.x;
    const int t = threadIdx.x;
    const int phase = bid % 5;

    if (phase < 4) {
        // ---------------- GEMM part ----------------
        const int gid = (bid / 5) * 4 + phase;
        if (gid >= GEMM_BLOCKS) return;
        float (*xs)[DIM] = (float (*)[DIM])smem;     // 40x100 floats = 16000 B
        const int row0 = gid * ROWS_PB;

        for (int i = t; i < ROWS_PB * 25; i += 256) {
            const int r = i / 25, c4 = (i - r * 25) * 4;
            const float4 v = *reinterpret_cast<const float4*>(
                &x[(size_t)(row0 + r) * DIM + c4]);
            *reinterpret_cast<float4*>(&xs[r][c4]) = v;
        }
        __syncthreads();

        if (t < 250) {
            const int g  = t / 25;            // row group 0..9
            const int c4 = (t - g * 25) * 4;  // col chunk
            const float4 bv = *reinterpret_cast<const float4*>(&b[c4]);
            float4 a0 = bv, a1 = bv, a2 = bv, a3 = bv;

            #pragma unroll 4
            for (int k = 0; k < DIM; ++k) {
                const float4 wv = *reinterpret_cast<const float4*>(&Wt[k * DIM + c4]);
                const float x0 = xs[g     ][k];
                const float x1 = xs[g + 10][k];
                const float x2 = xs[g + 20][k];
                const float x3 = xs[g + 30][k];
                a0.x += x0 * wv.x; a0.y += x0 * wv.y; a0.z += x0 * wv.z; a0.w += x0 * wv.w;
                a1.x += x1 * wv.x; a1.y += x1 * wv.y; a1.z += x1 * wv.z; a1.w += x1 * wv.w;
                a2.x += x2 * wv.x; a2.y += x2 * wv.y; a2.z += x2 * wv.z; a2.w += x2 * wv.w;
                a3.x += x3 * wv.x; a3.y += x3 * wv.y; a3.z += x3 * wv.z; a3.w += x3 * wv.w;
            }
            const int u0 = c4 >> 1;           // uint index within row
            uint2 p;
            p.x = bf16pair(a0.x, a0.y); p.y = bf16pair(a0.z, a0.w);
            *reinterpret_cast<uint2*>(&hidU[(size_t)(row0 + g     ) * 50 + u0]) = p;
            p.x = bf16pair(a1.x, a1.y); p.y = bf16pair(a1.z, a1.w);
            *reinterpret_cast<uint2*>(&hidU[(size_t)(row0 + g + 10) * 50 + u0]) = p;
            p.x = bf16pair(a2.x, a2.y); p.y = bf16pair(a2.z, a2.w);
            *reinterpret_cast<uint2*>(&hidU[(size_t)(row0 + g + 20) * 50 + u0]) = p;
            p.x = bf16pair(a3.x, a3.y); p.y = bf16pair(a3.z, a3.w);
            *reinterpret_cast<uint2*>(&hidU[(size_t)(row0 + g + 30) * 50 + u0]) = p;
        }
    } else {
        // ---------------- bin part ----------------
        const int kb = bid / 5;                      // 0..312
        if (kb >= BIN_BLOCKS) return;
        int* hist = (int*)smem;                      // NB ints
        int* lcur = hist + NB;                       // NB ints (12504 B total)
        const int e0 = kb * EPB;

        for (int i = t; i < NB; i += 256) hist[i] = 0;
        __syncthreads();

        int d[10];
        #pragma unroll
        for (int k = 0; k < 10; ++k) {
            const int e = e0 + t + k * 256;
            d[k] = (e < N_EDGES) ? edst[e] : -1;
            if (d[k] >= 0) atomicAdd(&hist[d[k] >> 5], 1);
        }
        __syncthreads();
        for (int i = t; i < NB; i += 256)
            if (hist[i]) lcur[i] = atomicAdd(&gcur[i], hist[i]);
        __syncthreads();
        #pragma unroll
        for (int k = 0; k < 10; ++k) {
            if (d[k] >= 0) {
                const int e = e0 + t + k * 256;
                const int s = esrc[e];
                const float w = ew[e];
                const int bq = d[k] >> 5;
                const int pos = atomicAdd(&lcur[bq], 1);
                if (pos < CAPB) {
                    bkt2[(size_t)bq * CAPB + pos] =
                        make_uint2((unsigned)s | bf16hi(w), (unsigned)d[k]);
                } else {
                    const int op = atomicAdd(ovfc, 1);
                    if (op < OVF_CAP) ovf[op] = make_int4(d[k], s, __float_as_int(w), 0);
                }
            }
        }
    }
}

// ---------------- aggregate: block per 32-node bucket, LDS counting sort --
__global__ __launch_bounds__(256) void srgnn_agg_s32(
    const unsigned* __restrict__ hidU, const int* __restrict__ gcur,
    const uint2* __restrict__ bkt2, const int* __restrict__ ovfc,
    const int4* __restrict__ ovf, float* __restrict__ out)
{
    __shared__ uint2    recs[CAPB];     // 6144 B
    __shared__ unsigned srt[CAPB];      // 3072 B
    __shared__ int nh[32], sc[32], cur[32];

    const int t = threadIdx.x;
    const int bq = blockIdx.x;
    int cntb = gcur[bq];
    if (cntb > CAPB) cntb = CAPB;

    if (t < 32) nh[t] = 0;
    __syncthreads();
    for (int i = t; i < cntb; i += 256) {
        const uint2 r = bkt2[(size_t)bq * CAPB + i];
        recs[i] = r;
        atomicAdd(&nh[r.y & 31], 1);
    }
    __syncthreads();
    if (t < 32) sc[t] = nh[t];
    __syncthreads();
    for (int ofs = 1; ofs < 32; ofs <<= 1) {         // Hillis-Steele inclusive
        int a = 0;
        if (t < 32 && t >= ofs) a = sc[t - ofs];
        __syncthreads();
        if (t < 32) sc[t] += a;
        __syncthreads();
    }
    if (t < 32) cur[t] = sc[t] - nh[t];
    __syncthreads();
    for (int i = t; i < cntb; i += 256) {
        const uint2 r = recs[i];
        const int pos = atomicAdd(&cur[r.y & 31], 1);
        srt[pos] = r.x;                              // src | bf16(w)<<16
    }
    __syncthreads();

    int oc = *ovfc;                                  // ~always 0
    if (oc > OVF_CAP) oc = OVF_CAP;
    const int lane = t & 63;
    const int wid  = t >> 6;                         // 4 waves
    const bool active = (lane < 50);

    for (int q = 0; q < 8; ++q) {
        const int n  = wid * 8 + q;                  // 4 waves x 8 = 32 nodes
        const int s1 = sc[n];
        const int s0 = s1 - nh[n];
        float2 acc = make_float2(0.f, 0.f);

        int p = s0;
        for (; p + 8 <= s1; p += 8) {                // 8-deep MLP
            unsigned r[8], h[8];
            #pragma unroll
            for (int j = 0; j < 8; ++j) r[j] = srt[p + j];
            if (active) {
                #pragma unroll
                for (int j = 0; j < 8; ++j)
                    h[j] = hidU[(size_t)(r[j] & 0xFFFFu) * 50 + lane];
                #pragma unroll
                for (int j = 0; j < 8; ++j) {
                    const float wj = __uint_as_float(r[j] & 0xFFFF0000u);
                    acc.x += wj * __uint_as_float(h[j] << 16);
                    acc.y += wj * __uint_as_float(h[j] & 0xFFFF0000u);
                }
            }
        }
        for (; p < s1; ++p) {
            const unsigned r = srt[p];
            const float wi = __uint_as_float(r & 0xFFFF0000u);
            if (active) {
                const unsigned h = hidU[(size_t)(r & 0xFFFFu) * 50 + lane];
                acc.x += wi * __uint_as_float(h << 16);
                acc.y += wi * __uint_as_float(h & 0xFFFF0000u);
            }
        }

        const int ng = bq * 32 + n;
        if (oc > 0) {                                // ultra-rare overflow scan
            for (int i = 0; i < oc; ++i) {
                const int4 v = ovf[i];
                if (v.x == ng && active) {
                    const unsigned h = hidU[(size_t)v.y * 50 + lane];
                    const float wi = __int_as_float(v.z);
                    acc.x += wi * __uint_as_float(h << 16);
                    acc.y += wi * __uint_as_float(h & 0xFFFF0000u);
                }
            }
        }
        if (ng < N_NODES && active)
            *reinterpret_cast<float2*>(&out[(size_t)ng * DIM + 2 * lane]) = acc;
    }
}

// ---------------- fallback (atomic scatter, needs only 20MB ws) ----------
__global__ __launch_bounds__(256) void srgnn_gemm_bias(
    const float* __restrict__ x, const float* __restrict__ W,
    const float* __restrict__ b, float* __restrict__ hidden)
{
    __shared__ float Wt[DIM][DIM + 4];
    __shared__ float bs[DIM];
    __shared__ float xs[8][DIM];
    const int t = threadIdx.x;
    for (int i = t; i < DIM * DIM; i += 256) {
        int c = i / DIM, k = i - c * DIM;
        Wt[k][c] = W[i];
    }
    if (t < DIM) bs[t] = b[t];
    const int row0 = blockIdx.x * 8;
    for (int i = t; i < 8 * DIM; i += 256) {
        int r = i / DIM, k = i - r * DIM;
        int row = row0 + r;
        xs[r][k] = (row < N_NODES) ? x[row * DIM + k] : 0.0f;
    }
    __syncthreads();
    if (t < 200) {
        const int r  = t / 25;
        const int c4 = (t - r * 25) * 4;
        float acc0 = bs[c4 + 0], acc1 = bs[c4 + 1], acc2 = bs[c4 + 2], acc3 = bs[c4 + 3];
        for (int k = 0; k < DIM; ++k) {
            const float xv = xs[r][k];
            const float4 wv = *reinterpret_cast<const float4*>(&Wt[k][c4]);
            acc0 += xv * wv.x; acc1 += xv * wv.y; acc2 += xv * wv.z; acc3 += xv * wv.w;
        }
        const int row = row0 + r;
        if (row < N_NODES)
            *reinterpret_cast<float4*>(&hidden[row * DIM + c4]) =
                make_float4(acc0, acc1, acc2, acc3);
    }
}

__global__ __launch_bounds__(256) void srgnn_scatter_atomic(
    const float* __restrict__ hidden, const int* __restrict__ esrc,
    const int* __restrict__ edst, const float* __restrict__ ew,
    float* __restrict__ out)
{
    const unsigned gid = blockIdx.x * 256u + threadIdx.x;
    const unsigned e = gid / 25u;
    const unsigned j = gid - e * 25u;
    if (e >= N_EDGES) return;
    const int   s  = esrc[e];
    const int   d  = edst[e];
    const float wt = ew[e];
    const float4 h = *reinterpret_cast<const float4*>(&hidden[(size_t)s * DIM + j * 4]);
    float* op = &out[(size_t)d * DIM + j * 4];
    atomicAdd(op + 0, h.x * wt);
    atomicAdd(op + 1, h.y * wt);
    atomicAdd(op + 2, h.z * wt);
    atomicAdd(op + 3, h.w * wt);
}

extern "C" void kernel_launch(void* const* d_in, const int* in_sizes, int n_in,
                              void* d_out, int out_size, void* d_ws, size_t ws_size,
                              hipStream_t stream) {
    const float* x    = (const float*)d_in[0];
    const int*   esrc = (const int*)  d_in[1];
    const int*   edst = (const int*)  d_in[2];
    const float* ew   = (const float*)d_in[3];
    const float* W    = (const float*)d_in[4];
    const float* b    = (const float*)d_in[5];
    float* out = (float*)d_out;

    char* ws = (char*)d_ws;

    if (ws_size >= WS_NEED) {
        unsigned* hidU = (unsigned*)(ws + HIDB_OFF);
        int*      gcur = (int*)     (ws + GCUR_OFF);
        int*      ovfc = (int*)     (ws + OVFC_OFF);
        int4*     ovf  = (int4*)    (ws + OVF_OFF);
        uint2*    bkt2 = (uint2*)   (ws + BKT2_OFF);
        float*    Wt   = (float*)   (ws + WT_OFF);

        // transpose W + zero control buffers (one dispatch)
        srgnn_transpose<<<(DIM * DIM + 255) / 256, 256, 0, stream>>>(W, Wt, gcur, ovfc);
        // fused + interleaved: gemm (1250 blocks) and bin (313 blocks)
        // period-5 role pattern -> both roles co-resident on every CU.
        const int fused_blocks = 5 * 313;   // covers gemm_id<1250 & bin_id<313
        srgnn_gemm_bin<<<fused_blocks, 256, 0, stream>>>(
            x, Wt, b, hidU, esrc, edst, ew, gcur, ovfc, ovf, bkt2);
        // block-per-bucket LDS sort + aggregate
        srgnn_agg_s32<<<NB, 256, 0, stream>>>(hidU, gcur, bkt2, ovfc, ovf, out);
    } else {
        // fallback: atomic scatter
        float* hidden = (float*)ws;
        hipMemsetAsync(d_out, 0, (size_t)out_size * sizeof(float), stream);
        const int gemm_blocks = (N_NODES + 7) / 8;
        srgnn_gemm_bias<<<gemm_blocks, 256, 0, stream>>>(x, W, b, hidden);
        const long long work = (long long)N_EDGES * 25;
        const int scat_blocks = (int)((work + 255) / 256);
        srgnn_scatter_atomic<<<scat_blocks, 256, 0, stream>>>(hidden, esrc, edst, ew, out);
    }
}